// Round 1
// baseline (2995.307 us; speedup 1.0000x reference)
//
#include <hip/hip_runtime.h>
#include <hip/hip_bf16.h>
#include <math.h>

typedef __bf16 bf16;
typedef float  floatx4 __attribute__((ext_vector_type(4)));
typedef bf16   bf16x8  __attribute__((ext_vector_type(8)));
typedef bf16   bf16x4  __attribute__((ext_vector_type(4)));

#define NB   32
#define NS   512
#define NIN  64
#define ND   512
#define NH   8
#define NL   4
#define NFF  2048
#define NTOK (NB * NS)   // 16384 tokens

__device__ __forceinline__ void gl_lds16(const void* g, void* l) {
  __builtin_amdgcn_global_load_lds(
      (const __attribute__((address_space(1))) unsigned int*)g,
      (__attribute__((address_space(3))) unsigned int*)l, 16, 0, 0);
}

__device__ __forceinline__ float gelu_f(float x) {
  return 0.5f * x * (1.0f + erff(x * 0.70710678118654752f));
}

// ---------------- fp32 -> bf16 conversion (weights + input) ----------------
__global__ __launch_bounds__(256) void cvt_kernel(const float* __restrict__ src,
                                                  bf16* __restrict__ dst, int n4) {
  int i = blockIdx.x * 256 + threadIdx.x;
  if (i < n4) {
    float4 v = ((const float4*)src)[i];
    bf16x4 o;
    o.x = (bf16)v.x; o.y = (bf16)v.y; o.z = (bf16)v.z; o.w = (bf16)v.w;
    ((bf16x4*)dst)[i] = o;
  }
}

// ---------------- generic bf16 MFMA GEMM: C[m,n] = sum_k A[m,k]*Bw[n,k] + bias[n]
// EPI 0: write fp32 Cf   EPI 1: write bf16 Cb   EPI 2: gelu -> bf16 Cb
// EPI 3: + positional encoding, write BOTH Cf (fp32) and Cb (bf16)
template <int EPI>
__global__ __launch_bounds__(256)
void gemm_bt(const bf16* __restrict__ A, const bf16* __restrict__ Bw,
             const float* __restrict__ bias, float* __restrict__ Cf,
             bf16* __restrict__ Cb, int N, int K) {
  __shared__ bf16 As[128 * 32];
  __shared__ bf16 Bs[128 * 32];
  const int tid   = threadIdx.x;
  const int wave  = tid >> 6;
  const int lane  = tid & 63;
  const int mlane = lane & 15, quad = lane >> 4;
  const int m0 = blockIdx.y * 128, n0 = blockIdx.x * 128;
  const int wm = (wave >> 1) * 64, wn = (wave & 1) * 64;

  // staging map: thread covers 16B = 8 bf16; row = tid>>2 (+64 for 2nd issue)
  const int srow = tid >> 2;
  const int scol = (tid & 3) * 8;
  const bf16* Ag0 = A  + (size_t)(m0 + srow) * K + scol;
  const bf16* Ag1 = Ag0 + (size_t)64 * K;
  const bf16* Bg0 = Bw + (size_t)(n0 + srow) * K + scol;
  const bf16* Bg1 = Bg0 + (size_t)64 * K;
  bf16* Al0 = As + tid * 8;
  bf16* Al1 = As + 2048 + tid * 8;
  bf16* Bl0 = Bs + tid * 8;
  bf16* Bl1 = Bs + 2048 + tid * 8;

  floatx4 zero = {0.0f, 0.0f, 0.0f, 0.0f};
  floatx4 acc[4][4];
#pragma unroll
  for (int i = 0; i < 4; ++i)
#pragma unroll
    for (int j = 0; j < 4; ++j) acc[i][j] = zero;

  for (int k0 = 0; k0 < K; k0 += 32) {
    __syncthreads();
    gl_lds16(Ag0 + k0, Al0);
    gl_lds16(Ag1 + k0, Al1);
    gl_lds16(Bg0 + k0, Bl0);
    gl_lds16(Bg1 + k0, Bl1);
    __builtin_amdgcn_s_waitcnt(0);
    __syncthreads();
    bf16x8 af[4], bfr[4];
#pragma unroll
    for (int mt = 0; mt < 4; ++mt)
      af[mt] = *(const bf16x8*)(As + (wm + mt * 16 + mlane) * 32 + quad * 8);
#pragma unroll
    for (int nt = 0; nt < 4; ++nt)
      bfr[nt] = *(const bf16x8*)(Bs + (wn + nt * 16 + mlane) * 32 + quad * 8);
#pragma unroll
    for (int mt = 0; mt < 4; ++mt)
#pragma unroll
      for (int nt = 0; nt < 4; ++nt)
        acc[mt][nt] = __builtin_amdgcn_mfma_f32_16x16x32_bf16(
            af[mt], bfr[nt], acc[mt][nt], 0, 0, 0);
  }

#pragma unroll
  for (int nt = 0; nt < 4; ++nt) {
    const int col = n0 + wn + nt * 16 + mlane;
    const float bv = bias[col];
#pragma unroll
    for (int mt = 0; mt < 4; ++mt) {
      const int row = m0 + wm + mt * 16 + quad * 4;
#pragma unroll
      for (int r = 0; r < 4; ++r) {
        float v = acc[mt][nt][r] + bv;
        if (EPI == 2) v = gelu_f(v);
        if (EPI == 3) {
          const int s  = (row + r) & (NS - 1);  // token index within sequence
          const int i2 = col & ~1;
          float div = expf((float)i2 * (-9.210340371976184f / 512.0f));
          float ang = (float)s * div;
          v += (col & 1) ? cosf(ang) : sinf(ang);
          Cf[(size_t)(row + r) * N + col] = v;
          Cb[(size_t)(row + r) * N + col] = (bf16)v;
        } else if (EPI == 0) {
          Cf[(size_t)(row + r) * N + col] = v;
        } else {
          Cb[(size_t)(row + r) * N + col] = (bf16)v;
        }
      }
    }
  }
}

// ---------------- transpose V head-wise: vT[b][h][d][s] = qkv[b][s][1024+h*64+d]
__global__ __launch_bounds__(256) void vtrans(const bf16* __restrict__ qkv,
                                              bf16* __restrict__ vT) {
  __shared__ bf16 T[64][65];
  const int b = blockIdx.z, h = blockIdx.y, s0 = blockIdx.x * 64;
#pragma unroll
  for (int it = 0; it < 16; ++it) {
    int idx = it * 256 + threadIdx.x;
    int si = idx >> 6, d = idx & 63;
    T[d][si] = qkv[(size_t)(b * NS + s0 + si) * 1536 + 1024 + h * 64 + d];
  }
  __syncthreads();
#pragma unroll
  for (int it = 0; it < 16; ++it) {
    int idx = it * 256 + threadIdx.x;
    int d = idx >> 6, sj = idx & 63;
    vT[(size_t)((b * NH + h) * 64 + d) * NS + s0 + sj] = T[d][sj];
  }
}

// ---------------- fused attention: scores -> softmax -> probs(fp32 to d_out) -> P@V
// grid (8 qblocks, H, B), 4 waves/block, each wave owns 16 q rows.
__global__ __launch_bounds__(256)
void attn_fused(const bf16* __restrict__ qkv, const bf16* __restrict__ vT,
                float* __restrict__ probs, bf16* __restrict__ ctx) {
  __shared__ bf16 P[4][16 * 512];
  const int tid = threadIdx.x;
  const int w = tid >> 6, lane = tid & 63;
  const int mlane = lane & 15, quad = lane >> 4;
  const int b = blockIdx.z, h = blockIdx.y;
  const int qt = blockIdx.x * 64 + w * 16;

  const bf16* qbase = qkv + (size_t)b * NS * 1536 + h * 64;
  const bf16* kbase = qbase + 512;

  const int qrow = qt + mlane;
  bf16x8 qf0 = *(const bf16x8*)(qbase + (size_t)qrow * 1536 + quad * 8);
  bf16x8 qf1 = *(const bf16x8*)(qbase + (size_t)qrow * 1536 + 32 + quad * 8);

  floatx4 acc[32];
#pragma unroll
  for (int kt = 0; kt < 32; ++kt) {
    const bf16* kr = kbase + (size_t)(kt * 16 + mlane) * 1536 + quad * 8;
    bf16x8 kf0 = *(const bf16x8*)kr;
    bf16x8 kf1 = *(const bf16x8*)(kr + 32);
    floatx4 a = {0.0f, 0.0f, 0.0f, 0.0f};
    a = __builtin_amdgcn_mfma_f32_16x16x32_bf16(qf0, kf0, a, 0, 0, 0);
    a = __builtin_amdgcn_mfma_f32_16x16x32_bf16(qf1, kf1, a, 0, 0, 0);
    acc[kt] = a;
  }

  // softmax (scale 1/sqrt(64)=0.125 folded in); rows quad*4+r, cols kt*16+mlane
  float mx[4] = {-1e30f, -1e30f, -1e30f, -1e30f};
#pragma unroll
  for (int kt = 0; kt < 32; ++kt)
#pragma unroll
    for (int r = 0; r < 4; ++r) mx[r] = fmaxf(mx[r], acc[kt][r]);
#pragma unroll
  for (int off = 1; off < 16; off <<= 1)
#pragma unroll
    for (int r = 0; r < 4; ++r) mx[r] = fmaxf(mx[r], __shfl_xor(mx[r], off));

  float sum[4] = {0.0f, 0.0f, 0.0f, 0.0f};
#pragma unroll
  for (int kt = 0; kt < 32; ++kt)
#pragma unroll
    for (int r = 0; r < 4; ++r) {
      float e = __expf((acc[kt][r] - mx[r]) * 0.125f);
      acc[kt][r] = e;
      sum[r] += e;
    }
#pragma unroll
  for (int off = 1; off < 16; off <<= 1)
#pragma unroll
    for (int r = 0; r < 4; ++r) sum[r] += __shfl_xor(sum[r], off);

  float rinv[4];
#pragma unroll
  for (int r = 0; r < 4; ++r) rinv[r] = 1.0f / sum[r];

  float* pbase = probs + ((size_t)((b * NH + h) * NS) + qt + quad * 4) * NS + mlane;
  bf16*  Pl    = &P[w][0] + (quad * 4) * 512 + mlane;
#pragma unroll
  for (int kt = 0; kt < 32; ++kt)
#pragma unroll
    for (int r = 0; r < 4; ++r) {
      float p = acc[kt][r] * rinv[r];
      pbase[(size_t)r * NS + kt * 16] = p;   // fp32 probs to d_out
      Pl[r * 512 + kt * 16] = (bf16)p;       // bf16 copy for PV (A-layout source)
    }

  __builtin_amdgcn_s_waitcnt(0);

  // ctx[q,d] = sum_k P[q,k] * V[k,d]   (B operand from vT[d][k], contiguous in k)
  const bf16* vbase = vT + (size_t)(b * NH + h) * 64 * NS;
  floatx4 c[4];
#pragma unroll
  for (int nt = 0; nt < 4; ++nt) c[nt] = (floatx4){0.0f, 0.0f, 0.0f, 0.0f};
#pragma unroll
  for (int ks = 0; ks < 16; ++ks) {
    bf16x8 af = *(const bf16x8*)(&P[w][0] + mlane * 512 + ks * 32 + quad * 8);
#pragma unroll
    for (int nt = 0; nt < 4; ++nt) {
      bf16x8 bv = *(const bf16x8*)(vbase + (size_t)(nt * 16 + mlane) * NS + ks * 32 + quad * 8);
      c[nt] = __builtin_amdgcn_mfma_f32_16x16x32_bf16(af, bv, c[nt], 0, 0, 0);
    }
  }
#pragma unroll
  for (int nt = 0; nt < 4; ++nt) {
    const int d = h * 64 + nt * 16 + mlane;
#pragma unroll
    for (int r = 0; r < 4; ++r)
      ctx[(size_t)(b * NS + qt + quad * 4 + r) * ND + d] = (bf16)c[nt][r];
  }
}

// ---------------- residual + layernorm: xo = LN(x + t)*w + b ; writes fp32 + bf16
__global__ __launch_bounds__(256)
void ln_res(const float* __restrict__ x, const float* __restrict__ t,
            const float* __restrict__ w, const float* __restrict__ bp,
            float* __restrict__ xo, bf16* __restrict__ xob) {
  const int row = blockIdx.x;
  const int tid = threadIdx.x;
  const size_t base = (size_t)row * ND;
  const int i = tid * 2;
  float2 xv = *(const float2*)(x + base + i);
  float2 tv = *(const float2*)(t + base + i);
  float a  = xv.x + tv.x;
  float b2 = xv.y + tv.y;
  float s  = a + b2;
  float sq = a * a + b2 * b2;
#pragma unroll
  for (int off = 1; off < 64; off <<= 1) {
    s  += __shfl_xor(s, off);
    sq += __shfl_xor(sq, off);
  }
  __shared__ float red[8];
  const int wv = tid >> 6, lane = tid & 63;
  if (lane == 0) { red[wv * 2] = s; red[wv * 2 + 1] = sq; }
  __syncthreads();
  s  = red[0] + red[2] + red[4] + red[6];
  sq = red[1] + red[3] + red[5] + red[7];
  const float mean = s * (1.0f / 512.0f);
  const float var  = sq * (1.0f / 512.0f) - mean * mean;
  const float rs   = rsqrtf(var + 1e-5f);
  float y0 = (a  - mean) * rs * w[i]     + bp[i];
  float y1 = (b2 - mean) * rs * w[i + 1] + bp[i + 1];
  *(float2*)(xo + base + i) = make_float2(y0, y1);
  xob[base + i]     = (bf16)y0;
  xob[base + i + 1] = (bf16)y1;
}

// ---------------- pooling (mean + max over S) ----------------
__global__ void pool1(const float* __restrict__ x, float* __restrict__ psum,
                      float* __restrict__ pmax) {
  const int c = blockIdx.x, b = blockIdx.y;
  const int d = threadIdx.x;  // 512
  float s = 0.0f, m = -1e30f;
  for (int i = 0; i < 64; ++i) {
    float v = x[(size_t)(b * NS + c * 64 + i) * ND + d];
    s += v;
    m = fmaxf(m, v);
  }
  psum[(b * 8 + c) * ND + d] = s;
  pmax[(b * 8 + c) * ND + d] = m;
}

__global__ void pool2(const float* __restrict__ psum, const float* __restrict__ pmax,
                      float* __restrict__ pooled) {
  const int b = blockIdx.x, d = threadIdx.x;
  float s = 0.0f, m = -1e30f;
  for (int c = 0; c < 8; ++c) {
    s += psum[(b * 8 + c) * ND + d];
    m = fmaxf(m, pmax[(b * 8 + c) * ND + d]);
  }
  pooled[b * 1024 + d] = s * (1.0f / 512.0f);
  pooled[b * 1024 + 512 + d] = m;
}

// ---------------- head ----------------
__global__ __launch_bounds__(256)
void head1_k(const float* __restrict__ pooled, const float* __restrict__ w,
             const float* __restrict__ bias, float* __restrict__ h1) {
  const int b = blockIdx.x;
  __shared__ float pl[1024];
  for (int i = threadIdx.x; i < 1024; i += 256) pl[i] = pooled[b * 1024 + i];
  __syncthreads();
  for (int j = threadIdx.x; j < 512; j += 256) {
    const float* wr = w + (size_t)j * 1024;
    float acc = 0.0f;
    for (int c = 0; c < 1024; c += 4) {
      float4 wv = *(const float4*)(wr + c);
      acc += pl[c] * wv.x + pl[c + 1] * wv.y + pl[c + 2] * wv.z + pl[c + 3] * wv.w;
    }
    acc += bias[j];
    h1[b * 512 + j] = gelu_f(acc);
  }
}

__global__ void head2_k(const float* __restrict__ h1, const float* __restrict__ w2,
                        const float* __restrict__ b2, float* __restrict__ out) {
  const int b = blockIdx.x;
  const int lane = threadIdx.x;  // 64
  float acc = 0.0f;
  for (int j = lane; j < 512; j += 64) acc += h1[b * 512 + j] * w2[j];
#pragma unroll
  for (int off = 1; off < 64; off <<= 1) acc += __shfl_xor(acc, off);
  if (lane == 0) out[b] = acc + b2[0];
}

// ---------------- launcher ----------------
extern "C" void kernel_launch(void* const* d_in, const int* in_sizes, int n_in,
                              void* d_out, int out_size, void* d_ws, size_t ws_size,
                              hipStream_t stream) {
  const float* x_in = (const float*)d_in[0];
  const float* w_in = (const float*)d_in[1];
  const float* b_in = (const float*)d_in[2];
  const float* inpW = (const float*)d_in[3];
  const float* inpB = (const float*)d_in[4];
  const float* outW = (const float*)d_in[5];
  const float* outB = (const float*)d_in[6];
  const float* ln1w = (const float*)d_in[7];
  const float* ln1b = (const float*)d_in[8];
  const float* ln2w = (const float*)d_in[9];
  const float* ln2b = (const float*)d_in[10];
  const float* ff1W = (const float*)d_in[11];
  const float* ff1B = (const float*)d_in[12];
  const float* ff2W = (const float*)d_in[13];
  const float* ff2B = (const float*)d_in[14];
  const float* h1W  = (const float*)d_in[15];
  const float* h1B  = (const float*)d_in[16];
  const float* h2W  = (const float*)d_in[17];
  const float* h2B  = (const float*)d_in[18];

  char* ws = (char*)d_ws;
  size_t off = 0;
  auto alloc = [&](size_t bytes) {
    void* p = ws + off;
    off = (off + bytes + 255) & ~(size_t)255;
    return p;
  };
  bf16*  winB   = (bf16*)alloc((size_t)ND * NIN * 2);
  bf16*  inpWb  = (bf16*)alloc((size_t)NL * 1536 * 512 * 2);
  bf16*  outWb  = (bf16*)alloc((size_t)NL * 512 * 512 * 2);
  bf16*  ff1Wb  = (bf16*)alloc((size_t)NL * 2048 * 512 * 2);
  bf16*  ff2Wb  = (bf16*)alloc((size_t)NL * 512 * 2048 * 2);
  bf16*  xinb   = (bf16*)alloc((size_t)NTOK * NIN * 2);
  float* xf     = (float*)alloc((size_t)NTOK * ND * 4);
  bf16*  xb     = (bf16*)alloc((size_t)NTOK * ND * 2);
  bf16*  qkv    = (bf16*)alloc((size_t)NTOK * 1536 * 2);  // 48 MB (256B-multiple)
  bf16*  ctx    = (bf16*)alloc((size_t)NTOK * ND * 2);    // 16 MB, contiguous after qkv
  bf16*  vT     = (bf16*)alloc((size_t)NB * NH * 64 * NS * 2);
  float* tmp    = (float*)alloc((size_t)NTOK * ND * 4);
  float* psum   = (float*)alloc((size_t)NB * 8 * ND * 4);
  float* pmax   = (float*)alloc((size_t)NB * 8 * ND * 4);
  float* pooled = (float*)alloc((size_t)NB * 1024 * 4);
  float* h1     = (float*)alloc((size_t)NB * 512 * 4);
  bf16* hbuf = qkv;  // FF hidden (16384x2048 bf16 = 64MB) reuses qkv(48)+ctx(16)

  dim3 blk(256);
  auto cvt = [&](const float* s, bf16* dd, size_t n) {
    int n4 = (int)(n / 4);
    cvt_kernel<<<dim3((n4 + 255) / 256), blk, 0, stream>>>(s, dd, n4);
  };
  cvt(w_in, winB, (size_t)ND * NIN);
  cvt(inpW, inpWb, (size_t)NL * 1536 * 512);
  cvt(outW, outWb, (size_t)NL * 512 * 512);
  cvt(ff1W, ff1Wb, (size_t)NL * 2048 * 512);
  cvt(ff2W, ff2Wb, (size_t)NL * 512 * 2048);
  cvt(x_in, xinb, (size_t)NTOK * NIN);

  // input projection + positional encoding -> xf (fp32) + xb (bf16)
  gemm_bt<3><<<dim3(ND / 128, NTOK / 128), blk, 0, stream>>>(
      xinb, winB, b_in, xf, xb, ND, NIN);

  float* out_head  = (float*)d_out;
  float* probs_all = (float*)d_out + 32;

  for (int l = 0; l < NL; ++l) {
    gemm_bt<1><<<dim3(1536 / 128, NTOK / 128), blk, 0, stream>>>(
        xb, inpWb + (size_t)l * 1536 * 512, inpB + l * 1536, nullptr, qkv, 1536, 512);
    vtrans<<<dim3(8, NH, NB), blk, 0, stream>>>(qkv, vT);
    attn_fused<<<dim3(8, NH, NB), blk, 0, stream>>>(
        qkv, vT, probs_all + (size_t)l * NB * NH * NS * NS, ctx);
    gemm_bt<0><<<dim3(ND / 128, NTOK / 128), blk, 0, stream>>>(
        ctx, outWb + (size_t)l * 512 * 512, outB + l * 512, tmp, nullptr, ND, 512);
    ln_res<<<dim3(NTOK), blk, 0, stream>>>(xf, tmp, ln1w + l * 512, ln1b + l * 512, xf, xb);
    gemm_bt<2><<<dim3(NFF / 128, NTOK / 128), blk, 0, stream>>>(
        xb, ff1Wb + (size_t)l * 2048 * 512, ff1B + l * 2048, nullptr, hbuf, NFF, 512);
    gemm_bt<0><<<dim3(ND / 128, NTOK / 128), blk, 0, stream>>>(
        hbuf, ff2Wb + (size_t)l * 512 * 2048, ff2B + l * 512, tmp, nullptr, ND, 2048);
    ln_res<<<dim3(NTOK), blk, 0, stream>>>(xf, tmp, ln2w + l * 512, ln2b + l * 512, xf, xb);
  }

  pool1<<<dim3(8, NB), dim3(512), 0, stream>>>(xf, psum, pmax);
  pool2<<<dim3(NB), dim3(512), 0, stream>>>(psum, pmax, pooled);
  head1_k<<<dim3(NB), blk, 0, stream>>>(pooled, h1W, h1B, h1);
  head2_k<<<dim3(NB), dim3(64), 0, stream>>>(h1, h2W, h2B, out_head);
}